// Round 4
// baseline (119.699 us; speedup 1.0000x reference)
//
#include <hip/hip_runtime.h>

// ClusteringAffinity: out[n,c] = exp(-min_j (f[n]-W[c,j])^2 / 10) for c<100,
// out[n,100] = rw (pairwise-variance regularizer over the 500 centers).
//
// R1: scalar dword stores (COLS=101 odd) ran writes at ~1-2 TB/s.
// R2: 64x101 LDS tile + contiguous 16B-aligned float4 stream -> ~6.3 TB/s.
// R3 (regressed): rw fused as a BLOCKING prologue (all 8 waves idled).
// R4 (117.9): rw fused at zero cost on wave 7 (idle in the compute mapping):
// fp64 power-sum butterfly, no divides, lane r writes tile[r*101+100].
// R5 (this round): ROWS=128 (half the blocks/barriers, 2x longer store
// streams; LDS 51712 B -> 3 blocks/CU, 24 waves/CU, still BW-saturating) +
// nontemporal float4 stores (output 105.9 MB is 3.3x aggregate L2 -> write-
// around avoids L2 thrash).

static constexpr int N_    = 262144;
static constexpr int C_    = 100;
static constexpr int M_    = 5;
static constexpr int COLS  = C_ + 1;       // 101
static constexpr int MC_   = C_ * M_;      // 500
static constexpr int ROWS  = 128;          // rows per tile/block
static constexpr int TILE  = ROWS * COLS;  // 12928 floats = 51712 B (16B-aligned tiles)
static constexpr float SIGMA_INV = 0.1f;

typedef float f32x4 __attribute__((ext_vector_type(4)));

__global__ __launch_bounds__(512)
void fused_affinity_kernel(const float* __restrict__ f,
                           const float* __restrict__ W,
                           float* __restrict__ out) {
    __shared__ __align__(16) float tile[TILE];
    const int t  = threadIdx.x;
    const int n0 = blockIdx.x * ROWS;

    if (t < 400) {
        // ---- distance columns: thread owns column c for 32 rows ----
        const int rq = t / 100;                   // row quarter: rows rq*32..rq*32+31
        const int c  = t - rq * 100;              // 0..99
        const int r0 = rq * 32;

        // 32 consecutive f values: 8 aligned float4 loads (L1-broadcast across threads)
        float fv[32];
        const float4* f4 = (const float4*)(f + n0 + r0);
#pragma unroll
        for (int q = 0; q < 8; ++q) {
            const float4 v = f4[q];
            fv[q * 4 + 0] = v.x; fv[q * 4 + 1] = v.y;
            fv[q * 4 + 2] = v.z; fv[q * 4 + 3] = v.w;
        }

        const float w0 = W[c * M_ + 0];
        const float w1 = W[c * M_ + 1];
        const float w2 = W[c * M_ + 2];
        const float w3 = W[c * M_ + 3];
        const float w4 = W[c * M_ + 4];

        float* trow = tile + r0 * COLS + c;
#pragma unroll
        for (int i = 0; i < 32; ++i) {
            const float fk = fv[i];
            const float d0 = fk - w0, d1 = fk - w1, d2 = fk - w2,
                        d3 = fk - w3, d4 = fk - w4;
            const float m01 = fminf(d0 * d0, d1 * d1);
            const float m23 = fminf(d2 * d2, d3 * d3);
            const float mv  = fminf(fminf(m01, m23), d4 * d4);
            trow[i * COLS] = __expf(-mv * SIGMA_INV);  // consecutive-c lanes -> no conflict
        }
    } else if (t >= 448) {
        // ---- rw column: wave 7 (otherwise idle) computes the regularizer ----
        // Closed form from power sums p1..p4 (fp64 for the S1 = mc*p2 - p1^2
        // cancellation): sum_{i<j}(wi-wj)^2 = mc*p2 - p1^2,
        //               sum_{i<j}(wi-wj)^4 = mc*p4 - 4*p3*p1 + 3*p2^2.
        const int l = t - 448;                    // lane 0..63 of wave 7
        double p1 = 0.0, p2 = 0.0, p3 = 0.0, p4 = 0.0;
#pragma unroll
        for (int k = 0; k < 8; ++k) {
            const int idx = l + 64 * k;
            const double w = (idx < MC_) ? (double)W[idx] : 0.0;
            const double w2 = w * w;
            p1 += w; p2 += w2; p3 += w2 * w; p4 += w2 * w2;
        }
#pragma unroll
        for (int m = 32; m >= 1; m >>= 1) {       // butterfly: all lanes get totals
            p1 += __shfl_xor(p1, m, 64);
            p2 += __shfl_xor(p2, m, 64);
            p3 += __shfl_xor(p3, m, 64);
            p4 += __shfl_xor(p4, m, 64);
        }
        const double mc   = (double)MC_;
        const double PINV = 1.0 / 124750.0;       // 1 / (0.5*(mc^2-mc)), no fp64 div
        const double S1 = mc * p2 - p1 * p1;
        const double Sq = mc * p4 - 4.0 * p3 * p1 + 3.0 * p2 * p2;
        const double mu = S1 * PINV;
        const float  rw = (float)(Sq * PINV - mu * mu);
        // lane l -> rows l and l+64, col 100; stride 101 across lanes (101%32=5,
        // coprime with 32) -> 2 lanes/bank, conflict-free.
        tile[l * COLS + C_]        = rw;
        tile[(l + 64) * COLS + C_] = rw;
    }
    __syncthreads();

    // ---- store phase: stream tile to global as aligned nontemporal float4 ----
    const f32x4* lsrc = (const f32x4*)tile;
    f32x4* gdst = (f32x4*)(out + (size_t)n0 * COLS);  // blk*51712 B, 16B-aligned
    constexpr int NV = TILE / 4;  // 3232 float4s
#pragma unroll
    for (int q = 0; q < 6; ++q) {
        const int j = q * 512 + t;
        __builtin_nontemporal_store(lsrc[j], gdst + j);
    }
    {
        const int j = 6 * 512 + t;
        if (j < NV) __builtin_nontemporal_store(lsrc[j], gdst + j);
    }
}

extern "C" void kernel_launch(void* const* d_in, const int* in_sizes, int n_in,
                              void* d_out, int out_size, void* d_ws, size_t ws_size,
                              hipStream_t stream) {
    const float* f   = (const float*)d_in[0];   // (262144, 1) fp32
    const float* W   = (const float*)d_in[1];   // (100, 5, 1) fp32
    float*       out = (float*)d_out;           // (262144, 101) fp32
    (void)d_ws; (void)ws_size;

    fused_affinity_kernel<<<N_ / ROWS, 512, 0, stream>>>(f, W, out);
}

// Round 5
// 118.885 us; speedup vs baseline: 1.0068x; 1.0068x over previous
//
#include <hip/hip_runtime.h>

// ClusteringAffinity: out[n,c] = exp(-min_j (f[n]-W[c,j])^2 / 10) for c<100,
// out[n,100] = rw (pairwise-variance regularizer over the 500 centers).
//
// R1: scalar dword stores (COLS=101 odd) ran writes at ~1-2 TB/s.
// R2: 64x101 LDS tile + contiguous 16B-aligned float4 stream -> ~6.3 TB/s.
// R3 (regressed): rw fused as a BLOCKING prologue (all 8 waves idled).
// R4 (117.9 us, best): rw fused at zero cost on wave 7 (idle in the compute
// mapping): fp64 power-sum butterfly, no divides, lane r writes tile[r*101+100].
// R5 (119.7): ROWS=128 + nontemporal stores — within run-to-run noise
// (fills alone drift +-3 us) but not better; reverting the bundle.
// R6 (this round): exact R4 kernel restored. Kernel is ~18-20 us vs a 17 us
// mandatory write floor (105.9 MB @ 6.3 TB/s); remainder of the timed region
// is the harness poison fill (~67 us, itself at the HBM roofline) + resets.

static constexpr int N_    = 262144;
static constexpr int C_    = 100;
static constexpr int M_    = 5;
static constexpr int COLS  = C_ + 1;       // 101
static constexpr int MC_   = C_ * M_;      // 500
static constexpr int ROWS  = 64;           // rows per tile/block
static constexpr int TILE  = ROWS * COLS;  // 6464 floats = 25856 B (16B-aligned tiles)
static constexpr float SIGMA_INV = 0.1f;

__global__ __launch_bounds__(512)
void fused_affinity_kernel(const float* __restrict__ f,
                           const float* __restrict__ W,
                           float* __restrict__ out) {
    __shared__ __align__(16) float tile[TILE];
    const int t  = threadIdx.x;
    const int n0 = blockIdx.x * ROWS;

    if (t < 400) {
        // ---- distance columns: thread owns column c for 16 rows ----
        const int rq = t / 100;                   // row quarter: rows rq*16..rq*16+15
        const int c  = t - rq * 100;              // 0..99
        const int r0 = rq * 16;

        // 16 consecutive f values: 4 aligned float4 loads (L1-broadcast across threads)
        float fv[16];
        const float4* f4 = (const float4*)(f + n0 + r0);
#pragma unroll
        for (int q = 0; q < 4; ++q) {
            const float4 v = f4[q];
            fv[q * 4 + 0] = v.x; fv[q * 4 + 1] = v.y;
            fv[q * 4 + 2] = v.z; fv[q * 4 + 3] = v.w;
        }

        const float w0 = W[c * M_ + 0];
        const float w1 = W[c * M_ + 1];
        const float w2 = W[c * M_ + 2];
        const float w3 = W[c * M_ + 3];
        const float w4 = W[c * M_ + 4];

        float* trow = tile + r0 * COLS + c;
#pragma unroll
        for (int i = 0; i < 16; ++i) {
            const float fk = fv[i];
            const float d0 = fk - w0, d1 = fk - w1, d2 = fk - w2,
                        d3 = fk - w3, d4 = fk - w4;
            const float m01 = fminf(d0 * d0, d1 * d1);
            const float m23 = fminf(d2 * d2, d3 * d3);
            const float mv  = fminf(fminf(m01, m23), d4 * d4);
            trow[i * COLS] = __expf(-mv * SIGMA_INV);  // consecutive-c lanes -> no conflict
        }
    } else if (t >= 448) {
        // ---- rw column: wave 7 (otherwise idle) computes the regularizer ----
        // Closed form from power sums p1..p4 (fp64 for the S1 = mc*p2 - p1^2
        // cancellation): sum_{i<j}(wi-wj)^2 = mc*p2 - p1^2,
        //               sum_{i<j}(wi-wj)^4 = mc*p4 - 4*p3*p1 + 3*p2^2.
        const int l = t - 448;                    // lane 0..63 of wave 7
        double p1 = 0.0, p2 = 0.0, p3 = 0.0, p4 = 0.0;
#pragma unroll
        for (int k = 0; k < 8; ++k) {
            const int idx = l + 64 * k;
            const double w = (idx < MC_) ? (double)W[idx] : 0.0;
            const double w2 = w * w;
            p1 += w; p2 += w2; p3 += w2 * w; p4 += w2 * w2;
        }
#pragma unroll
        for (int m = 32; m >= 1; m >>= 1) {       // butterfly: all lanes get totals
            p1 += __shfl_xor(p1, m, 64);
            p2 += __shfl_xor(p2, m, 64);
            p3 += __shfl_xor(p3, m, 64);
            p4 += __shfl_xor(p4, m, 64);
        }
        const double mc   = (double)MC_;
        const double PINV = 1.0 / 124750.0;       // 1 / (0.5*(mc^2-mc)), no fp64 div
        const double S1 = mc * p2 - p1 * p1;
        const double Sq = mc * p4 - 4.0 * p3 * p1 + 3.0 * p2 * p2;
        const double mu = S1 * PINV;
        const float  rw = (float)(Sq * PINV - mu * mu);
        // lane r -> row r, col 100; addr stride 101 across lanes (101%32=5,
        // coprime with 32) -> 2 lanes/bank, conflict-free.
        tile[l * COLS + C_] = rw;
    }
    __syncthreads();

    // ---- store phase: stream tile to global as aligned contiguous float4 ----
    const float4* lsrc = (const float4*)tile;
    float4* gdst = (float4*)(out + (size_t)n0 * COLS);  // blk*25856 B, 16B-aligned
    constexpr int NV = TILE / 4;  // 1616 float4s
#pragma unroll
    for (int q = 0; q < 3; ++q) {
        const int j = q * 512 + t;
        gdst[j] = lsrc[j];
    }
    {
        const int j = 3 * 512 + t;
        if (j < NV) gdst[j] = lsrc[j];
    }
}

extern "C" void kernel_launch(void* const* d_in, const int* in_sizes, int n_in,
                              void* d_out, int out_size, void* d_ws, size_t ws_size,
                              hipStream_t stream) {
    const float* f   = (const float*)d_in[0];   // (262144, 1) fp32
    const float* W   = (const float*)d_in[1];   // (100, 5, 1) fp32
    float*       out = (float*)d_out;           // (262144, 101) fp32
    (void)d_ws; (void)ws_size;

    fused_affinity_kernel<<<N_ / ROWS, 512, 0, stream>>>(f, W, out);
}